// Round 16
// baseline (64.231 us; speedup 1.0000x reference)
//
#include <hip/hip_runtime.h>
#include <hip/hip_bf16.h>
#include <math.h>

// Problem constants
constexpr int kB = 256, kC = 512, kT = 56, kP = 512;
constexpr int kCT = kC * kT;  // 28672 floats per row

typedef short v4s __attribute__((ext_vector_type(4)));
typedef short v8s __attribute__((ext_vector_type(8)));
typedef float v4f __attribute__((ext_vector_type(4)));
typedef float v16f __attribute__((ext_vector_type(16)));

__device__ __forceinline__ unsigned pack_bf16(float a, float b) {
  __hip_bfloat16 ha = __float2bfloat16(a);
  __hip_bfloat16 hb = __float2bfloat16(b);
  unsigned short ua, ub;
  __builtin_memcpy(&ua, &ha, 2);
  __builtin_memcpy(&ub, &hb, 2);
  return (unsigned)ua | ((unsigned)ub << 16);
}

__device__ __forceinline__ v4s frag2(unsigned w0, unsigned w1) {
  unsigned u[2] = {w0, w1};
  v4s s;
  __builtin_memcpy(&s, u, 8);
  return s;
}

__device__ __forceinline__ v8s frag8(uint4 u) {
  v8s s;
  __builtin_memcpy(&s, &u, 16);
  return s;
}

// bf16x2 word -> f32 halves
__device__ __forceinline__ float bfl(unsigned u) {
  unsigned v = u << 16;
  float f;
  __builtin_memcpy(&f, &v, 4);
  return f;
}
__device__ __forceinline__ float bfh(unsigned u) {
  unsigned v = u & 0xffff0000u;
  float f;
  __builtin_memcpy(&f, &v, 4);
  return f;
}
// pack two f32 -> bf16x2 word (RNE), lo = s0  [HW-verified r7/r14/r15]
__device__ __forceinline__ unsigned cvtpk(float lo, float hi) {
  unsigned r;
  asm("v_cvt_pk_bf16_f32 %0, %1, %2" : "=v"(r) : "v"(lo), "v"(hi));
  return r;
}

// global->LDS DMA, 16B per lane; LDS dest = wave-uniform base + lane*16
// (linear). Read-side XOR swizzle realized by pre-swizzling the per-lane
// GLOBAL source chunk (both-sides-or-neither; XOR is an involution).
#define GLOAD(gp, lp)                                                        \
  __builtin_amdgcn_global_load_lds(                                          \
      (const __attribute__((address_space(1))) unsigned*)(const unsigned*)(gp), \
      (__attribute__((address_space(3))) unsigned*)(unsigned*)(lp), 16, 0, 0)

// ===========================================================================
// WS word layout (t4-blocked, r15-verified):
//   xt word( row, t, cg ) = (t>>2)*kB*1024 + row*1024 + (cg>>6)*256
//                           + (t&3)*64 + (cg&63)
//   pt same with kP.  cg = c-word index 0..255 (c_global = 2*cg).
// ===========================================================================

// ===========================================================================
// PREP v8 = r15 minus xwt: one source row per block (grid 768), 4 c-chunks.
// b128 LDS stage writes (stride-64 XOR swizzle), dwordx4 coalesced 1 KB
// global stores, cvt_pk_bf16, register norm partials, no atomics.
// ===========================================================================
__global__ __launch_bounds__(512) void prep_kernel(
    const float* __restrict__ x, const float* __restrict__ proto,
    unsigned* __restrict__ xt, unsigned* __restrict__ pt,
    float* __restrict__ xn2, float* __restrict__ pn2) {
  __shared__ float tile[128 * 64];   // 32,768 B
  __shared__ float normp[56 * 16];   // 3,584 B

  const int tid = threadIdx.x;
  const int n = blockIdx.x;        // source row 0..767
  const bool isx = (n < kB);
  const int row = isx ? n : (n - kB);
  const float* src = (isx ? x : proto) + (size_t)row * kCT;
  const int R = isx ? kB : kP;
  unsigned* dst0 = isx ? xt : pt;

  const int l = tid & 63;
  const int w = tid >> 6;          // wave 0..7
  const int j = l & 15;            // c-group (8 c each) within chunk
  const int tq = l >> 4;           // 0..3

  float na0 = 0.f, na1 = 0.f;      // norm partials for pass 0 / pass 1

#pragma unroll 1
  for (int ch = 0; ch < 4; ++ch) {
    const float* csrc = src + ch * (128 * 56);

    // ---- stage: 1792 float4 coalesced reads -> b128 LDS writes (swizzled)
#pragma unroll
    for (int it = 0; it < 4; ++it) {
      const int idx = it * 512 + tid;
      if (idx < 1792) {
        const int f0 = idx * 4;
        const int c = (int)(((unsigned)f0 * 74899u) >> 22);  // f0 / 56
        const int t = f0 - c * 56;  // multiple of 4 (56%4==0)
        const int sw = ((((unsigned)c >> 3) ^ (unsigned)c) & 7) << 2;
        float4 v = *(const float4*)(csrc + f0);
        *(float4*)(tile + c * 64 + (t ^ sw)) = v;  // t^sw in [0,64)
      }
    }
    __syncthreads();

    // ---- pack + norm partials: 2 passes over t; task (t, j)
#pragma unroll
    for (int pass = 0; pass < 2; ++pass) {
      const int t = pass * 32 + w * 4 + tq;
      if (t < 56) {
        float f[8];
#pragma unroll
        for (int i = 0; i < 8; ++i) {
          const int sw = ((j ^ i) & 7) << 2;  // == sw_c for c = 8j+i
          f[i] = tile[(8 * j + i) * 64 + (t ^ sw)];
        }
        float s = 0.f;
#pragma unroll
        for (int i = 0; i < 8; ++i) s = fmaf(f[i], f[i], s);
        if (pass == 0) na0 += s; else na1 += s;
        uint4 wx;
        wx.x = cvtpk(f[0], f[1]);
        wx.y = cvtpk(f[2], f[3]);
        wx.z = cvtpk(f[4], f[5]);
        wx.w = cvtpk(f[6], f[7]);
        // coalesced 1 KB burst per wave per buffer
        const size_t o = (size_t)(t >> 2) * ((size_t)R * 1024) +
                         (size_t)row * 1024 + ch * 256 + (t & 3) * 64 + 4 * j;
        *(uint4*)(dst0 + o) = wx;
      }
    }
    __syncthreads();  // tile reused next chunk
  }

  // norm finish (single writer; no atomics)
  {
    const int t0 = w * 4 + tq;
    normp[t0 * 16 + j] = na0;
    const int t1 = 32 + w * 4 + tq;
    if (t1 < 56) normp[t1 * 16 + j] = na1;
  }
  __syncthreads();
  if (tid < 56) {
    float s = 0.f;
#pragma unroll
    for (int k = 0; k < 16; ++k) s += normp[tid * 16 + k];
    if (isx) xn2[row * 56 + tid] = s;
    else     pn2[row * 56 + tid] = s;
  }
}

// ===========================================================================
// MAIN v9: xwt ELIMINATED. Block 64b x 64p x 4t, 4 waves of 32b x 32p
// (mfma 32x32x16), grid 448 (XCD-bijective). 32 stages of 64 c; DMA stages
// only xt + pt (4 GLOADs/wave/stage) into FOUR 16 KB buffers (64 KB) —
// depth-3 prefetch, steady-state vmcnt(8) (2 stages x 4 loads in flight).
// W-operand built in-register: fcw packed once into LDS (fcwL, 1 KB, same
// bf16x2 word order as xt); per ks: wf.word = cvtpk(bfl(x)*bfl(f),
// bfh(x)*bfh(f)). fcwL reads are 2-address broadcasts (conflict-free).
// Phase: { vmcnt(8); s_barrier; COMPUTE(s, s&3); STAGE(s+3, (s+3)&3) } —
// buffer (s+3)&3 = (s-1)&3 was computed at s-1, protected by barrier(s).
// ===========================================================================
constexpr int TILE = 64 * 32;   // one tile: 2048 words (8 KB)
constexpr int BUF = 2 * TILE;   // x + p = 4096 words (16 KB)

__global__ __launch_bounds__(256, 2) void proto_gemm_kernel(
    const unsigned* __restrict__ xt, const unsigned* __restrict__ pt,
    const float* __restrict__ fcw,
    const float* __restrict__ xn2, const float* __restrict__ pn2,
    float* __restrict__ part) {
  __shared__ __align__(16) unsigned lds[4 * BUF];  // 65,536 B
  __shared__ unsigned fcwL[256];                   // 1 KB (bf16x2, xt order)
  __shared__ float xnL[4 * 64], pnL[4 * 64];       // 2 KB

  const int tid = threadIdx.x;
  const int l = tid & 63;
  const int w4 = tid >> 6;    // wave 0..3
  const int wm = w4 >> 1;     // b half
  const int wn = w4 & 1;      // p half

  // bijective XCD swizzle (448 = 8*56)
  int bid = (int)blockIdx.x;
  bid = (bid & 7) * 56 + (bid >> 3);
  const int b0 = (bid & 3) * 64;
  const int p0 = ((bid >> 2) & 7) * 64;
  const int tg = bid >> 5;    // 0..13 ; t = tg*4 .. tg*4+3

  // norms + fcw table -> LDS; no DMA yet so a full sync is fine
  {
    const int tl = tid >> 6, r = tid & 63;
    xnL[tid] = sqrtf(xn2[(b0 + r) * 56 + tg * 4 + tl]);
    pnL[tid] = sqrtf(pn2[(p0 + r) * 56 + tg * 4 + tl]);
    fcwL[tid] = pack_bf16(fcw[2 * tid], fcw[2 * tid + 1]);
  }
  __syncthreads();

  // staging geometry: per tile-stage (64 rows x 32 words), wave w4 stages
  // rows [w4*16, w4*16+16): 2 DMA calls, call j covers rows w4*16+j*8+(l>>3),
  // 16B chunk (l&7). Global source chunk = (l&7) ^ (row&7) [inverse swizzle].
  // t4 layout: row stride 1024 words.
  const int lrow = l >> 3, lch = l & 7;
  size_t xsrc[2], psrc[2];
  int ldst[2];
#pragma unroll
  for (int j = 0; j < 2; ++j) {
    const int row = w4 * 16 + j * 8 + lrow;
    const int ch4 = ((lch ^ (row & 7))) * 4;
    xsrc[j] = (size_t)(b0 + row) * 1024 + ch4;
    psrc[j] = (size_t)(p0 + row) * 1024 + ch4;
    ldst[j] = (w4 * 16 + j * 8) * 32;  // wave-uniform LDS word offset
  }

  // fragment geometry (32x32x16: lane -> row fr=l&31, k-half hi=l>>5)
  const int fr = l & 31;
  const int hi = l >> 5;
  const int axb = (wm * 32 + fr) * 32;  // x row base (words)
  const int pxb = (wn * 32 + fr) * 32;  // p row base
  const int frs = fr & 7;               // read-side chunk XOR

  v16f aD, aW, sac, nac;
#pragma unroll
  for (int i = 0; i < 16; ++i) { aD[i] = 0.f; aW[i] = 0.f; sac[i] = 0.f; nac[i] = 0.f; }

  auto STAGE = [&](int s, int buf) {
    const int t = tg * 4 + (s >> 3);
    const int kw = s & 7;
    const size_t base = (size_t)((t & 3) * 64) +
                        (size_t)((kw >> 1) * 256 + (kw & 1) * 32);
    const size_t xo = (size_t)(t >> 2) * ((size_t)kB * 1024) + base;
    const size_t po = (size_t)(t >> 2) * ((size_t)kP * 1024) + base;
    unsigned* lb = lds + buf * BUF;
#pragma unroll
    for (int j = 0; j < 2; ++j) {
      GLOAD(xt + xsrc[j] + xo, lb + ldst[j]);
      GLOAD(pt + psrc[j] + po, lb + TILE + ldst[j]);
    }
  };

  auto COMPUTE = [&](int s, int buf) {
    const unsigned* bx = lds + buf * BUF;
    const int kw = s & 7;
#pragma unroll
    for (int ks = 0; ks < 4; ++ks) {
      const int q = (ks << 1) | hi;
      const int col = (q ^ frs) << 2;
      uint4 xr = *(const uint4*)(bx + axb + col);
      uint4 pr = *(const uint4*)(bx + TILE + pxb + col);
      // fcw fragment: logical words kw*32 + q*4 .. +4 (broadcast read)
      uint4 fw = *(const uint4*)(fcwL + kw * 32 + (q << 2));
      uint4 wr;
      wr.x = cvtpk(bfl(xr.x) * bfl(fw.x), bfh(xr.x) * bfh(fw.x));
      wr.y = cvtpk(bfl(xr.y) * bfl(fw.y), bfh(xr.y) * bfh(fw.y));
      wr.z = cvtpk(bfl(xr.z) * bfl(fw.z), bfh(xr.z) * bfh(fw.z));
      wr.w = cvtpk(bfl(xr.w) * bfl(fw.w), bfh(xr.w) * bfh(fw.w));
      v8s xf = frag8(xr), wf = frag8(wr), pf = frag8(pr);
      aD = __builtin_amdgcn_mfma_f32_32x32x16_bf16(xf, pf, aD, 0, 0, 0);
      aW = __builtin_amdgcn_mfma_f32_32x32x16_bf16(wf, pf, aW, 0, 0, 0);
    }
    if ((s & 7) == 7) {
      // end of one t: sim = D/(xn*pn); sac += exp(sim); nac += exp(sim)*W.
      // |sim| <= 1 (cosine) -> exp bounded, no running max needed.
      const int tl = s >> 3;
      const float pnv = pnL[tl * 64 + wn * 32 + fr];
#pragma unroll
      for (int i = 0; i < 16; ++i) {
        const int drow = (i & 3) + 8 * (i >> 2) + 4 * hi;  // m74/m101 C/D map
        const float xnv = xnL[tl * 64 + wm * 32 + drow];
        float den = fmaxf(xnv * pnv, 1e-8f);
        float sim = aD[i] * __builtin_amdgcn_rcpf(den);
        float e = __expf(sim);
        sac[i] += e;
        nac[i] = fmaf(e, aW[i], nac[i]);
        aD[i] = 0.f;
        aW[i] = 0.f;
      }
    }
  };

  // prologue: fill the pipeline 3 deep
  STAGE(0, 0);
  STAGE(1, 1);
  STAGE(2, 2);

#pragma unroll 1
  for (int s = 0; s < 32; ++s) {
    // counted wait: stage-s loads (4/wave) complete; stages s+1, s+2 stay
    // in flight (8 = 2 stages x 4). vmcnt-then-barrier => collective.
    if (s < 30)      asm volatile("s_waitcnt vmcnt(8)" ::: "memory");
    else if (s == 30) asm volatile("s_waitcnt vmcnt(4)" ::: "memory");
    else              asm volatile("s_waitcnt vmcnt(0)" ::: "memory");
    __builtin_amdgcn_s_barrier();
    __builtin_amdgcn_sched_barrier(0);
    COMPUTE(s, s & 3);
    // stage s+3 into buffer (s+3)&3 = (s-1)&3, computed at s-1 — safe:
    // barrier(s) implies all waves completed COMPUTE(s-1).
    if (s < 29) STAGE(s + 3, (s + 3) & 3);
  }

  // write partials: part[(tg*2 + comp)*131072 + b*512 + p]
  float* psb = part + ((size_t)tg * 2 + 0) * 131072;
  float* pnb = part + ((size_t)tg * 2 + 1) * 131072;
#pragma unroll
  for (int i = 0; i < 16; ++i) {
    const int drow = (i & 3) + 8 * (i >> 2) + 4 * hi;
    const size_t o = (size_t)(b0 + wm * 32 + drow) * 512 + p0 + wn * 32 + fr;
    psb[o] = sac[i];
    pnb[o] = nac[i];
  }
}

// ===========================================================================
// MERGE: plain sums of the 14 t-group partials, bias, relu.
// ===========================================================================
__global__ __launch_bounds__(256) void merge_kernel(
    const float* __restrict__ part, const float* __restrict__ fcb,
    float* __restrict__ out) {
  const int pair = blockIdx.x * 256 + threadIdx.x;
  float S = 0.f, N = 0.f;
#pragma unroll
  for (int k = 0; k < 14; ++k) {
    S += part[((size_t)k * 2 + 0) * 131072 + pair];
    N += part[((size_t)k * 2 + 1) * 131072 + pair];
  }
  float o = N * __builtin_amdgcn_rcpf(S) + fcb[0];
  out[pair] = fmaxf(o, 0.f);
}

// ===========================================================================
// FALLBACK (round-2 kernel, used only if ws_size is too small)
// ===========================================================================
__global__ __launch_bounds__(1024) void proto_mfma_kernel(
    const float* __restrict__ x, const float* __restrict__ proto,
    const float* __restrict__ fcw, const float* __restrict__ fcb,
    float* __restrict__ out) {
  __shared__ unsigned xs[56 * 289];
  __shared__ unsigned ps[56 * 145];
  __shared__ unsigned pws[56 * 145];

  const int tid = threadIdx.x;
  const int l = tid & 63;
  const int w = tid >> 6;
  const int bq = w & 1;
  const int tq = w >> 1;
  const int t0 = tq * 7;

  const int n = blockIdx.y * 32 + blockIdx.x;
  const int p0 = (n >> 3) * 16;
  const int b0 = (n & 7) * 32;

  const bool act = (l < 56);
  const int lt = l;

  const int xbase0 = ((b0 + 2 * w + 0) * kC) * kT + lt;
  const int xbase1 = ((b0 + 2 * w + 1) * kC) * kT + lt;
  const int pbase = ((p0 + w) * kC) * kT + lt;

  const int arow = l & 15;
  const int q2 = (l >> 4) << 1;
  const int xoff = (bq * 16 + arow) * 9 + q2;
  const int poff = arow * 9 + q2;

  v4f acc[7][2];
#pragma unroll
  for (int ti = 0; ti < 7; ++ti) {
    acc[ti][0] = v4f{0.f, 0.f, 0.f, 0.f};
    acc[ti][1] = v4f{0.f, 0.f, 0.f, 0.f};
  }
  float xn2a = 0.f, xn2b = 0.f, pn2 = 0.f;

#pragma unroll 1
  for (int st = 0; st < 32; ++st) {
    const int k0 = st * 16;
    if (act) {
#pragma unroll
      for (int r = 0; r < 16; ++r) {
        const int cw = r & 7;
        const int c = k0 + 2 * cw;
        const int ga = ((r >> 3) ? xbase1 : xbase0) + c * kT;
        float g0 = x[ga], g1 = x[ga + kT];
        if (r >> 3) xn2b = fmaf(g0, g0, fmaf(g1, g1, xn2b));
        else xn2a = fmaf(g0, g0, fmaf(g1, g1, xn2a));
        xs[lt * 289 + (2 * w + (r >> 3)) * 9 + cw] = pack_bf16(g0, g1);
      }
#pragma unroll
      for (int cw = 0; cw < 8; ++cw) {
        const int c = k0 + 2 * cw;
        const int ga = pbase + c * kT;
        float g0 = proto[ga], g1 = proto[ga + kT];
        pn2 = fmaf(g0, g0, fmaf(g1, g1, pn2));
        ps[lt * 145 + w * 9 + cw] = pack_bf16(g0, g1);
        float f0 = fcw[c], f1 = fcw[c + 1];
        pws[lt * 145 + w * 9 + cw] = pack_bf16(g0 * f0, g1 * f1);
      }
    }
    __syncthreads();
#pragma unroll
    for (int ti = 0; ti < 7; ++ti) {
      const int t = t0 + ti;
      unsigned xw0 = xs[t * 289 + xoff];
      unsigned xw1 = xs[t * 289 + xoff + 1];
      unsigned pw0 = ps[t * 145 + poff];
      unsigned pw1 = ps[t * 145 + poff + 1];
      unsigned ww0 = pws[t * 145 + poff];
      unsigned ww1 = pws[t * 145 + poff + 1];
      v4s af = frag2(xw0, xw1);
      v4s bf = frag2(pw0, pw1);
      v4s wf = frag2(ww0, ww1);
      acc[ti][0] = __builtin_amdgcn_mfma_f32_16x16x16bf16_1k(af, bf, acc[ti][0], 0, 0, 0);
      acc[ti][1] = __builtin_amdgcn_mfma_f32_16x16x16bf16_1k(af, wf, acc[ti][1], 0, 0, 0);
    }
    __syncthreads();
  }

  float* xnorm = (float*)ps;
  float* pnorm = xnorm + 32 * 56;
  if (act) {
    xnorm[(2 * w + 0) * 56 + lt] = xn2a;
    xnorm[(2 * w + 1) * 56 + lt] = xn2b;
    pnorm[w * 56 + lt] = pn2;
  }
  __syncthreads();

  float* fm = (float*)xs;
  float* fsum = fm + 4096;
  float* fnum = fsum + 4096;
  const int pc = arow;
  const int qq = l >> 4;
#pragma unroll
  for (int i = 0; i < 4; ++i) {
    const int bl = bq * 16 + 4 * qq + i;
    float m = -3.0e38f;
    float sims[7];
#pragma unroll
    for (int ti = 0; ti < 7; ++ti) {
      const int t = t0 + ti;
      float den = fmaxf(sqrtf(xnorm[bl * 56 + t]) * sqrtf(pnorm[pc * 56 + t]), 1e-8f);
      float s = acc[ti][0][i] / den;
      sims[ti] = s;
      m = fmaxf(m, s);
    }
    float se = 0.f, nu = 0.f;
#pragma unroll
    for (int ti = 0; ti < 7; ++ti) {
      float e = __expf(sims[ti] - m);
      se += e;
      nu = fmaf(e, acc[ti][1][i], nu);
    }
    const int pair = bl * 16 + pc;
    fm[tq * 512 + pair] = m;
    fsum[tq * 512 + pair] = se;
    fnum[tq * 512 + pair] = nu;
  }
  __syncthreads();

  if (tid < 512) {
    float M = -3.0e38f;
#pragma unroll
    for (int k = 0; k < 8; ++k) M = fmaxf(M, fm[k * 512 + tid]);
    float S = 0.f, N = 0.f;
#pragma unroll
    for (int k = 0; k < 8; ++k) {
      float sc = __expf(fm[k * 512 + tid] - M);
      S = fmaf(fsum[k * 512 + tid], sc, S);
      N = fmaf(fnum[k * 512 + tid], sc, N);
    }
    float o = N / S + fcb[0];
    out[(b0 + (tid >> 4)) * kP + p0 + (tid & 15)] = fmaxf(o, 0.f);
  }
}

// ===========================================================================
extern "C" void kernel_launch(void* const* d_in, const int* in_sizes, int n_in,
                              void* d_out, int out_size, void* d_ws, size_t ws_size,
                              hipStream_t stream) {
  const float* x = (const float*)d_in[0];
  const float* proto = (const float*)d_in[1];
  const float* fcw = (const float*)d_in[2];
  const float* fcb = (const float*)d_in[3];
  float* out = (float*)d_out;

  // ws layout (words; xwt slot retained but unused to keep offsets stable):
  // xt 3,670,016 | (unused 3,670,016) | pt 7,340,032 | part 14*2*131072 |
  // xn2 14,336 | pn2 28,672  => 18,393,088 words = 73,572,352 B (granted)
  const size_t need = 73572352;
  if (ws_size >= need) {
    unsigned* xt = (unsigned*)d_ws;
    unsigned* ptb = xt + 7340032;
    float* partb = (float*)(xt + 14680064);
    float* xn2b = (float*)(xt + 18350080);
    float* pn2b = xn2b + 14336;

    hipLaunchKernelGGL(prep_kernel, dim3(kB + kP), dim3(512), 0, stream,
                       x, proto, xt, ptb, xn2b, pn2b);
    hipLaunchKernelGGL(proto_gemm_kernel, dim3(448), dim3(256), 0, stream,
                       xt, ptb, fcw, xn2b, pn2b, partb);
    hipLaunchKernelGGL(merge_kernel, dim3(512), dim3(256), 0, stream,
                       partb, fcb, out);
  } else {
    hipLaunchKernelGGL(proto_mfma_kernel, dim3(32, 8), dim3(1024), 0, stream,
                       x, proto, fcw, fcb, out);
  }
}

// Round 17
// 60.875 us; speedup vs baseline: 1.0551x; 1.0551x over previous
//
#include <hip/hip_runtime.h>
#include <hip/hip_bf16.h>
#include <math.h>

// Problem constants
constexpr int kB = 256, kC = 512, kT = 56, kP = 512;
constexpr int kCT = kC * kT;  // 28672 floats per row

typedef short v4s __attribute__((ext_vector_type(4)));
typedef short v8s __attribute__((ext_vector_type(8)));
typedef float v4f __attribute__((ext_vector_type(4)));
typedef float v16f __attribute__((ext_vector_type(16)));

__device__ __forceinline__ unsigned pack_bf16(float a, float b) {
  __hip_bfloat16 ha = __float2bfloat16(a);
  __hip_bfloat16 hb = __float2bfloat16(b);
  unsigned short ua, ub;
  __builtin_memcpy(&ua, &ha, 2);
  __builtin_memcpy(&ub, &hb, 2);
  return (unsigned)ua | ((unsigned)ub << 16);
}

__device__ __forceinline__ v4s frag2(unsigned w0, unsigned w1) {
  unsigned u[2] = {w0, w1};
  v4s s;
  __builtin_memcpy(&s, u, 8);
  return s;
}

__device__ __forceinline__ v8s frag8(uint4 u) {
  v8s s;
  __builtin_memcpy(&s, &u, 16);
  return s;
}

// pack two f32 -> bf16x2 word (RNE), lo = s0  [HW-verified r7/r14/r15]
__device__ __forceinline__ unsigned cvtpk(float lo, float hi) {
  unsigned r;
  asm("v_cvt_pk_bf16_f32 %0, %1, %2" : "=v"(r) : "v"(lo), "v"(hi));
  return r;
}

// global->LDS DMA, 16B per lane; LDS dest = wave-uniform base + lane*16
// (linear). Read-side XOR swizzle realized by pre-swizzling the per-lane
// GLOBAL source chunk (both-sides-or-neither; XOR is an involution).
#define GLOAD(gp, lp)                                                        \
  __builtin_amdgcn_global_load_lds(                                          \
      (const __attribute__((address_space(1))) unsigned*)(const unsigned*)(gp), \
      (__attribute__((address_space(3))) unsigned*)(unsigned*)(lp), 16, 0, 0)

// ===========================================================================
// WS word layout (t4-blocked so prep writes are 1 KB coalesced):
//   xt/xwt word( row, t, cg ) = (t>>2)*kB*1024 + row*1024 + (cg>>6)*256
//                               + (t&3)*64 + (cg&63)
//   pt  same with kP.  cg = c-word index 0..255 (c_global = 2*cg).
// prep: one wave's 64 lanes (tq=l>>4, j=l&15) write tq*64+4j -> 0..1023
//       words = ONE contiguous 1 KB burst per buffer.
// gemm: stage s window kw=s&7 covers cg in [kw*32, kw*32+32) -> base
//       (kw>>1)*256 + (kw&1)*32 (window inside one 64-word cg-group).
// ===========================================================================

// ===========================================================================
// PREP v7 (r15-verified): monolithic — one source row per block (grid 768,
// 3 blocks/CU all resident), 4 c-chunks looped. No atomics, no zero kernel
// (single writer per xn2/pn2 cell; norm partials in registers). Vectorized:
// b128 LDS stage writes (stride-64 XOR swizzle), dwordx4 coalesced 1 KB
// global stores, cvt_pk_bf16, fcw in registers (xwt fold at WRITE time —
// r16 proved fold-at-read costs gemm VALU).
// ===========================================================================
__global__ __launch_bounds__(512) void prep_kernel(
    const float* __restrict__ x, const float* __restrict__ proto,
    const float* __restrict__ fcw,
    unsigned* __restrict__ xt, unsigned* __restrict__ xwt,
    unsigned* __restrict__ pt,
    float* __restrict__ xn2, float* __restrict__ pn2) {
  __shared__ float tile[128 * 64];   // 32,768 B
  __shared__ float normp[56 * 16];   // 3,584 B

  const int tid = threadIdx.x;
  const int n = blockIdx.x;        // source row 0..767
  const bool isx = (n < kB);
  const int row = isx ? n : (n - kB);
  const float* src = (isx ? x : proto) + (size_t)row * kCT;
  const int R = isx ? kB : kP;
  unsigned* dst0 = isx ? xt : pt;

  const int l = tid & 63;
  const int w = tid >> 6;          // wave 0..7
  const int j = l & 15;            // c-group (8 c each) within chunk
  const int tq = l >> 4;           // 0..3

  float na0 = 0.f, na1 = 0.f;      // norm partials for pass 0 / pass 1

#pragma unroll 1
  for (int ch = 0; ch < 4; ++ch) {
    const float* csrc = src + ch * (128 * 56);

    // fcw for this thread's 8 c of this chunk (registers)
    float fw[8];
    if (isx) {
      const float* gf = fcw + ch * 128 + 8 * j;
#pragma unroll
      for (int i = 0; i < 8; ++i) fw[i] = gf[i];
    }

    // ---- stage: 1792 float4 coalesced reads -> b128 LDS writes (swizzled)
#pragma unroll
    for (int it = 0; it < 4; ++it) {
      const int idx = it * 512 + tid;
      if (idx < 1792) {
        const int f0 = idx * 4;
        const int c = (int)(((unsigned)f0 * 74899u) >> 22);  // f0 / 56
        const int t = f0 - c * 56;  // multiple of 4 (56%4==0)
        const int sw = ((((unsigned)c >> 3) ^ (unsigned)c) & 7) << 2;
        float4 v = *(const float4*)(csrc + f0);
        *(float4*)(tile + c * 64 + (t ^ sw)) = v;  // t^sw in [0,64)
      }
    }
    __syncthreads();

    // ---- pack + norm partials: 2 passes over t; task (t, j)
#pragma unroll
    for (int pass = 0; pass < 2; ++pass) {
      const int t = pass * 32 + w * 4 + tq;
      if (t < 56) {
        float f[8];
#pragma unroll
        for (int i = 0; i < 8; ++i) {
          const int sw = ((j ^ i) & 7) << 2;  // == sw_c for c = 8j+i
          f[i] = tile[(8 * j + i) * 64 + (t ^ sw)];
        }
        float s = 0.f;
#pragma unroll
        for (int i = 0; i < 8; ++i) s = fmaf(f[i], f[i], s);
        if (pass == 0) na0 += s; else na1 += s;
        uint4 wx;
        wx.x = cvtpk(f[0], f[1]);
        wx.y = cvtpk(f[2], f[3]);
        wx.z = cvtpk(f[4], f[5]);
        wx.w = cvtpk(f[6], f[7]);
        // coalesced 1 KB burst per wave per buffer
        const size_t o = (size_t)(t >> 2) * ((size_t)R * 1024) +
                         (size_t)row * 1024 + ch * 256 + (t & 3) * 64 + 4 * j;
        *(uint4*)(dst0 + o) = wx;
        if (isx) {
          uint4 ww;
          ww.x = cvtpk(f[0] * fw[0], f[1] * fw[1]);
          ww.y = cvtpk(f[2] * fw[2], f[3] * fw[3]);
          ww.z = cvtpk(f[4] * fw[4], f[5] * fw[5]);
          ww.w = cvtpk(f[6] * fw[6], f[7] * fw[7]);
          *(uint4*)(xwt + o) = ww;
        }
      }
    }
    __syncthreads();  // tile reused next chunk
  }

  // norm finish (single writer; no atomics)
  {
    const int t0 = w * 4 + tq;
    normp[t0 * 16 + j] = na0;
    const int t1 = 32 + w * 4 + tq;
    if (t1 < 56) normp[t1 * 16 + j] = na1;
  }
  __syncthreads();
  if (tid < 56) {
    float s = 0.f;
#pragma unroll
    for (int k = 0; k < 16; ++k) s += normp[tid * 16 + k];
    if (isx) xn2[row * 56 + tid] = s;
    else     pn2[row * 56 + tid] = s;
  }
}

// ===========================================================================
// MAIN (r15-verified): block 64b x 64p x 4t, 4 waves of 32b x 32p
// (mfma 32x32x16), grid 448 (XCD-bijective). 32 stages of 64 c; DMA staging
// of xt/xwt/pt, 3 x 24 KB buffers, 2 blocks/CU.
// Phase: { vmcnt(6); s_barrier; COMPUTE(s); STAGE(s+2) } — single barrier
// per phase, counted vmcnt, never 0 in the main loop.
// ===========================================================================
constexpr int TILE = 64 * 32;   // one tile: 2048 words (8 KB)
constexpr int BUF = 3 * TILE;   // x + xw + p = 6144 words (24 KB)

__global__ __launch_bounds__(256, 2) void proto_gemm_kernel(
    const unsigned* __restrict__ xt, const unsigned* __restrict__ xwt,
    const unsigned* __restrict__ pt,
    const float* __restrict__ xn2, const float* __restrict__ pn2,
    float* __restrict__ part) {
  __shared__ __align__(16) unsigned lds[3 * BUF];  // 73,728 B
  __shared__ float xnL[4 * 64], pnL[4 * 64];       // +2,048 B

  const int tid = threadIdx.x;
  const int l = tid & 63;
  const int w4 = tid >> 6;    // wave 0..3
  const int wm = w4 >> 1;     // b half
  const int wn = w4 & 1;      // p half

  // bijective XCD swizzle (448 = 8*56)
  int bid = (int)blockIdx.x;
  bid = (bid & 7) * 56 + (bid >> 3);
  const int b0 = (bid & 3) * 64;
  const int p0 = ((bid >> 2) & 7) * 64;
  const int tg = bid >> 5;    // 0..13 ; t = tg*4 .. tg*4+3

  // norms -> LDS (sqrt of summed squares); no DMA yet
  {
    const int tl = tid >> 6, r = tid & 63;
    xnL[tid] = sqrtf(xn2[(b0 + r) * 56 + tg * 4 + tl]);
    pnL[tid] = sqrtf(pn2[(p0 + r) * 56 + tg * 4 + tl]);
  }
  __syncthreads();

  // staging geometry: per tile-stage (64 rows x 32 words), wave w4 stages
  // rows [w4*16, w4*16+16): 2 DMA calls, call j covers rows w4*16+j*8+(l>>3),
  // 16B chunk (l&7). Global source chunk = (l&7) ^ (row&7) [inverse swizzle].
  // t4 layout: row stride 1024 words.
  const int lrow = l >> 3, lch = l & 7;
  size_t xsrc[2], psrc[2];
  int ldst[2];
#pragma unroll
  for (int j = 0; j < 2; ++j) {
    const int row = w4 * 16 + j * 8 + lrow;
    const int ch4 = ((lch ^ (row & 7))) * 4;
    xsrc[j] = (size_t)(b0 + row) * 1024 + ch4;
    psrc[j] = (size_t)(p0 + row) * 1024 + ch4;
    ldst[j] = (w4 * 16 + j * 8) * 32;  // wave-uniform LDS word offset
  }

  // fragment geometry (32x32x16: lane -> row fr=l&31, k-half hi=l>>5)
  const int fr = l & 31;
  const int hi = l >> 5;
  const int axb = (wm * 32 + fr) * 32;  // x/xw row base (words)
  const int pxb = (wn * 32 + fr) * 32;  // p row base
  const int frs = fr & 7;               // read-side chunk XOR

  v16f aD, aW, sac, nac;
#pragma unroll
  for (int i = 0; i < 16; ++i) { aD[i] = 0.f; aW[i] = 0.f; sac[i] = 0.f; nac[i] = 0.f; }

  auto STAGE = [&](int s, int buf) {
    const int t = tg * 4 + (s >> 3);
    const int kw = s & 7;
    const size_t base = (size_t)((t & 3) * 64) +
                        (size_t)((kw >> 1) * 256 + (kw & 1) * 32);
    const size_t xo = (size_t)(t >> 2) * ((size_t)kB * 1024) + base;
    const size_t po = (size_t)(t >> 2) * ((size_t)kP * 1024) + base;
    unsigned* lb = lds + buf * BUF;
#pragma unroll
    for (int j = 0; j < 2; ++j) {
      GLOAD(xt + xsrc[j] + xo, lb + ldst[j]);
      GLOAD(xwt + xsrc[j] + xo, lb + TILE + ldst[j]);
      GLOAD(pt + psrc[j] + po, lb + 2 * TILE + ldst[j]);
    }
  };

  auto COMPUTE = [&](int s, int buf) {
    const unsigned* bx = lds + buf * BUF;
#pragma unroll
    for (int ks = 0; ks < 4; ++ks) {
      const int col = (((ks << 1) | hi) ^ frs) << 2;
      v8s xf = frag8(*(const uint4*)(bx + axb + col));
      v8s wf = frag8(*(const uint4*)(bx + TILE + axb + col));
      v8s pf = frag8(*(const uint4*)(bx + 2 * TILE + pxb + col));
      aD = __builtin_amdgcn_mfma_f32_32x32x16_bf16(xf, pf, aD, 0, 0, 0);
      aW = __builtin_amdgcn_mfma_f32_32x32x16_bf16(wf, pf, aW, 0, 0, 0);
    }
    if ((s & 7) == 7) {
      // end of one t: sim = D/(xn*pn); sac += exp(sim); nac += exp(sim)*W.
      // |sim| <= 1 (cosine) -> exp bounded, no running max needed.
      const int tl = s >> 3;
      const float pnv = pnL[tl * 64 + wn * 32 + fr];
#pragma unroll
      for (int i = 0; i < 16; ++i) {
        const int drow = (i & 3) + 8 * (i >> 2) + 4 * hi;  // m74/m101 C/D map
        const float xnv = xnL[tl * 64 + wm * 32 + drow];
        float den = fmaxf(xnv * pnv, 1e-8f);
        float sim = aD[i] * __builtin_amdgcn_rcpf(den);
        float e = __expf(sim);
        sac[i] += e;
        nac[i] = fmaf(e, aW[i], nac[i]);
        aD[i] = 0.f;
        aW[i] = 0.f;
      }
    }
  };

  // prologue: fill the pipeline 2 deep
  STAGE(0, 0);
  STAGE(1, 1);

  int c0 = 0, c1 = 1, c2 = 2;  // compute buf, next buf, stage buf
#pragma unroll 1
  for (int s = 0; s < 32; ++s) {
    // counted wait: stage-s loads (6/wave) complete; stage s+1 stays in
    // flight. vmcnt-then-barrier => collective guarantee.
    if (s < 31) asm volatile("s_waitcnt vmcnt(6)" ::: "memory");
    else        asm volatile("s_waitcnt vmcnt(0)" ::: "memory");
    __builtin_amdgcn_s_barrier();
    __builtin_amdgcn_sched_barrier(0);
    COMPUTE(s, c0);
    // stage s+2 into the buffer computed at s-1 (safe: barrier(s) implies
    // all waves completed COMPUTE(s-1)).
    if (s < 30) STAGE(s + 2, c2);
    const int tmp = c0; c0 = c1; c1 = c2; c2 = tmp;
  }

  // write partials: part[(tg*2 + comp)*131072 + b*512 + p]
  float* psb = part + ((size_t)tg * 2 + 0) * 131072;
  float* pnb = part + ((size_t)tg * 2 + 1) * 131072;
#pragma unroll
  for (int i = 0; i < 16; ++i) {
    const int drow = (i & 3) + 8 * (i >> 2) + 4 * hi;
    const size_t o = (size_t)(b0 + wm * 32 + drow) * 512 + p0 + wn * 32 + fr;
    psb[o] = sac[i];
    pnb[o] = nac[i];
  }
}

// ===========================================================================
// MERGE: plain sums of the 14 t-group partials, bias, relu.
// ===========================================================================
__global__ __launch_bounds__(256) void merge_kernel(
    const float* __restrict__ part, const float* __restrict__ fcb,
    float* __restrict__ out) {
  const int pair = blockIdx.x * 256 + threadIdx.x;
  float S = 0.f, N = 0.f;
#pragma unroll
  for (int k = 0; k < 14; ++k) {
    S += part[((size_t)k * 2 + 0) * 131072 + pair];
    N += part[((size_t)k * 2 + 1) * 131072 + pair];
  }
  float o = N * __builtin_amdgcn_rcpf(S) + fcb[0];
  out[pair] = fmaxf(o, 0.f);
}

// ===========================================================================
// FALLBACK (round-2 kernel, used only if ws_size is too small)
// ===========================================================================
__global__ __launch_bounds__(1024) void proto_mfma_kernel(
    const float* __restrict__ x, const float* __restrict__ proto,
    const float* __restrict__ fcw, const float* __restrict__ fcb,
    float* __restrict__ out) {
  __shared__ unsigned xs[56 * 289];
  __shared__ unsigned ps[56 * 145];
  __shared__ unsigned pws[56 * 145];

  const int tid = threadIdx.x;
  const int l = tid & 63;
  const int w = tid >> 6;
  const int bq = w & 1;
  const int tq = w >> 1;
  const int t0 = tq * 7;

  const int n = blockIdx.y * 32 + blockIdx.x;
  const int p0 = (n >> 3) * 16;
  const int b0 = (n & 7) * 32;

  const bool act = (l < 56);
  const int lt = l;

  const int xbase0 = ((b0 + 2 * w + 0) * kC) * kT + lt;
  const int xbase1 = ((b0 + 2 * w + 1) * kC) * kT + lt;
  const int pbase = ((p0 + w) * kC) * kT + lt;

  const int arow = l & 15;
  const int q2 = (l >> 4) << 1;
  const int xoff = (bq * 16 + arow) * 9 + q2;
  const int poff = arow * 9 + q2;

  v4f acc[7][2];
#pragma unroll
  for (int ti = 0; ti < 7; ++ti) {
    acc[ti][0] = v4f{0.f, 0.f, 0.f, 0.f};
    acc[ti][1] = v4f{0.f, 0.f, 0.f, 0.f};
  }
  float xn2a = 0.f, xn2b = 0.f, pn2 = 0.f;

#pragma unroll 1
  for (int st = 0; st < 32; ++st) {
    const int k0 = st * 16;
    if (act) {
#pragma unroll
      for (int r = 0; r < 16; ++r) {
        const int cw = r & 7;
        const int c = k0 + 2 * cw;
        const int ga = ((r >> 3) ? xbase1 : xbase0) + c * kT;
        float g0 = x[ga], g1 = x[ga + kT];
        if (r >> 3) xn2b = fmaf(g0, g0, fmaf(g1, g1, xn2b));
        else xn2a = fmaf(g0, g0, fmaf(g1, g1, xn2a));
        xs[lt * 289 + (2 * w + (r >> 3)) * 9 + cw] = pack_bf16(g0, g1);
      }
#pragma unroll
      for (int cw = 0; cw < 8; ++cw) {
        const int c = k0 + 2 * cw;
        const int ga = pbase + c * kT;
        float g0 = proto[ga], g1 = proto[ga + kT];
        pn2 = fmaf(g0, g0, fmaf(g1, g1, pn2));
        ps[lt * 145 + w * 9 + cw] = pack_bf16(g0, g1);
        float f0 = fcw[c], f1 = fcw[c + 1];
        pws[lt * 145 + w * 9 + cw] = pack_bf16(g0 * f0, g1 * f1);
      }
    }
    __syncthreads();
#pragma unroll
    for (int ti = 0; ti < 7; ++ti) {
      const int t = t0 + ti;
      unsigned xw0 = xs[t * 289 + xoff];
      unsigned xw1 = xs[t * 289 + xoff + 1];
      unsigned pw0 = ps[t * 145 + poff];
      unsigned pw1 = ps[t * 145 + poff + 1];
      unsigned ww0 = pws[t * 145 + poff];
      unsigned ww1 = pws[t * 145 + poff + 1];
      v4s af = frag2(xw0, xw1);
      v4s bf = frag2(pw0, pw1);
      v4s wf = frag2(ww0, ww1);
      acc[ti][0] = __builtin_amdgcn_mfma_f32_16x16x16bf16_1k(af, bf, acc[ti][0], 0, 0, 0);
      acc[ti][1] = __builtin_amdgcn_mfma_f32_16x16x16bf16_1k(af, wf, acc[ti][1], 0, 0, 0);
    }
    __syncthreads();
  }

  float* xnorm = (float*)ps;
  float* pnorm = xnorm + 32 * 56;
  if (act) {
    xnorm[(2 * w + 0) * 56 + lt] = xn2a;
    xnorm[(2 * w + 1) * 56 + lt] = xn2b;
    pnorm[w * 56 + lt] = pn2;
  }
  __syncthreads();

  float* fm = (float*)xs;
  float* fsum = fm + 4096;
  float* fnum = fsum + 4096;
  const int pc = arow;
  const int qq = l >> 4;
#pragma unroll
  for (int i = 0; i < 4; ++i) {
    const int bl = bq * 16 + 4 * qq + i;
    float m = -3.0e38f;
    float sims[7];
#pragma unroll
    for (int ti = 0; ti < 7; ++ti) {
      const int t = t0 + ti;
      float den = fmaxf(sqrtf(xnorm[bl * 56 + t]) * sqrtf(pnorm[pc * 56 + t]), 1e-8f);
      float s = acc[ti][0][i] / den;
      sims[ti] = s;
      m = fmaxf(m, s);
    }
    float se = 0.f, nu = 0.f;
#pragma unroll
    for (int ti = 0; ti < 7; ++ti) {
      float e = __expf(sims[ti] - m);
      se += e;
      nu = fmaf(e, acc[ti][1][i], nu);
    }
    const int pair = bl * 16 + pc;
    fm[tq * 512 + pair] = m;
    fsum[tq * 512 + pair] = se;
    fnum[tq * 512 + pair] = nu;
  }
  __syncthreads();

  if (tid < 512) {
    float M = -3.0e38f;
#pragma unroll
    for (int k = 0; k < 8; ++k) M = fmaxf(M, fm[k * 512 + tid]);
    float S = 0.f, N = 0.f;
#pragma unroll
    for (int k = 0; k < 8; ++k) {
      float sc = __expf(fm[k * 512 + tid] - M);
      S = fmaf(fsum[k * 512 + tid], sc, S);
      N = fmaf(fnum[k * 512 + tid], sc, N);
    }
    float o = N / S + fcb[0];
    out[(b0 + (tid >> 4)) * kP + p0 + (tid & 15)] = fmaxf(o, 0.f);
  }
}

// ===========================================================================
extern "C" void kernel_launch(void* const* d_in, const int* in_sizes, int n_in,
                              void* d_out, int out_size, void* d_ws, size_t ws_size,
                              hipStream_t stream) {
  const float* x = (const float*)d_in[0];
  const float* proto = (const float*)d_in[1];
  const float* fcw = (const float*)d_in[2];
  const float* fcb = (const float*)d_in[3];
  float* out = (float*)d_out;

  // ws layout (words): xt 3,670,016 | xwt 3,670,016 | pt 7,340,032 |
  // part 14*2*131072 = 3,670,016 | xn2 14,336 | pn2 28,672
  //   => 18,393,088 words = 73,572,352 B  (granted; same as r11-r15)
  const size_t need = 73572352;
  if (ws_size >= need) {
    unsigned* xt = (unsigned*)d_ws;
    unsigned* xwt = xt + 3670016;
    unsigned* ptb = xt + 7340032;
    float* partb = (float*)(xt + 14680064);
    float* xn2b = (float*)(xt + 18350080);
    float* pn2b = xn2b + 14336;

    hipLaunchKernelGGL(prep_kernel, dim3(kB + kP), dim3(512), 0, stream,
                       x, proto, fcw, xt, xwt, ptb, xn2b, pn2b);
    hipLaunchKernelGGL(proto_gemm_kernel, dim3(448), dim3(256), 0, stream,
                       xt, xwt, ptb, xn2b, pn2b, partb);
    hipLaunchKernelGGL(merge_kernel, dim3(512), dim3(256), 0, stream,
                       partb, fcb, out);
  } else {
    hipLaunchKernelGGL(proto_mfma_kernel, dim3(32, 8), dim3(1024), 0, stream,
                       x, proto, fcw, fcb, out);
  }
}